// Round 1
// baseline (351.573 us; speedup 1.0000x reference)
//
#include <hip/hip_runtime.h>

#define P 7
#define PP 49            // 7*7 pixels per ROI
#define CMAX 256         // channels
#define ACTIVE 245       // 5 channels * 49 pixels per iteration

struct PixParam { int o00, o01, o10, o11; float w00, w01, w10, w11; };

__global__ __launch_bounds__(256) void roialign_kernel(
    const float* __restrict__ p2, const float* __restrict__ p3,
    const float* __restrict__ p4, const float* __restrict__ p5,
    const float* __restrict__ rois, float* __restrict__ out)
{
    __shared__ PixParam sp[PP];

    const int r = blockIdx.x;     // roi index in [0, B*R)
    const int t = threadIdx.x;

    // --- per-ROI params (computed redundantly by all threads; broadcast loads) ---
    const float x1 = rois[r * 4 + 0];
    const float y1 = rois[r * 4 + 1];
    const float x2 = rois[r * 4 + 2];
    const float y2 = rois[r * 4 + 3];

    const float area = __fmul_rn(__fsub_rn(y2, y1), __fsub_rn(x2, x1));
    int lvl = (int)rintf(log2f(sqrtf(fmaxf(area, 0.0f)) / 224.0f)) + 4;
    lvl = lvl < 2 ? 2 : (lvl > 5 ? 5 : lvl);
    const int H = 1024 >> lvl;          // square feature maps: W == H
    const int HW = H * H;
    const float* fm = (lvl == 2) ? p2 : (lvl == 3) ? p3 : (lvl == 4) ? p4 : p5;
    // image 0 only (reference uses feature_maps[i][0] for all rois)

    // --- per-pixel params into LDS (49 threads) ---
    if (t < PP) {
        const int py = t / P, px = t % P;
        const float inv = 1.0f / 1024.0f;                 // exact pow2
        const float by1 = __fmul_rn(y1, inv), bx1 = __fmul_rn(x1, inv);
        const float by2 = __fmul_rn(y2, inv), bx2 = __fmul_rn(x2, inv);
        const float Hm1 = (float)(H - 1);
        const float ty = (float)py / 6.0f;
        const float tx = (float)px / 6.0f;
        // match numpy op-for-op (no fma contraction)
        const float vy = __fmul_rn(__fadd_rn(by1, __fmul_rn(ty, __fsub_rn(by2, by1))), Hm1);
        const float vx = __fmul_rn(__fadd_rn(bx1, __fmul_rn(tx, __fsub_rn(bx2, bx1))), Hm1);
        const bool vldy = (vy >= 0.0f) && (vy <= Hm1);
        const bool vldx = (vx >= 0.0f) && (vx <= Hm1);
        const float yc = fminf(fmaxf(vy, 0.0f), Hm1);
        const float xc = fminf(fmaxf(vx, 0.0f), Hm1);
        const int y0 = (int)floorf(yc);
        const int x0 = (int)floorf(xc);
        const int y1i = min(y0 + 1, H - 1);
        const int x1i = min(x0 + 1, H - 1);
        const float ly = __fsub_rn(yc, (float)y0);
        const float lx = __fsub_rn(xc, (float)x0);
        const float m = (vldy && vldx) ? 1.0f : 0.0f;
        const float wy0 = m * (1.0f - ly), wy1 = m * ly;
        const float wx0 = 1.0f - lx,      wx1 = lx;
        PixParam pp;
        pp.o00 = y0 * H + x0;   pp.o01 = y0 * H + x1i;
        pp.o10 = y1i * H + x0;  pp.o11 = y1i * H + x1i;
        pp.w00 = wy0 * wx0;     pp.w01 = wy0 * wx1;
        pp.w10 = wy1 * wx0;     pp.w11 = wy1 * wx1;
        sp[t] = pp;
    }
    __syncthreads();

    if (t >= ACTIVE) return;
    const int pix = t % PP;
    const int c0  = t / PP;                 // 0..4
    const PixParam pp = sp[pix];

    const float* fmc = fm + (size_t)c0 * HW;
    float* outr = out + (size_t)r * (CMAX * PP);
    int idx = t;                            // == c0*49 + pix
    #pragma unroll 4
    for (int c = c0; c < CMAX; c += 5) {
        const float tl = fmc[pp.o00];
        const float tr = fmc[pp.o01];
        const float bl = fmc[pp.o10];
        const float br = fmc[pp.o11];
        outr[idx] = tl * pp.w00 + tr * pp.w01 + bl * pp.w10 + br * pp.w11;
        fmc += 5 * HW;
        idx += ACTIVE;
    }
}

extern "C" void kernel_launch(void* const* d_in, const int* in_sizes, int n_in,
                              void* d_out, int out_size, void* d_ws, size_t ws_size,
                              hipStream_t stream) {
    const float* p2   = (const float*)d_in[0];
    const float* p3   = (const float*)d_in[1];
    const float* p4   = (const float*)d_in[2];
    const float* p5   = (const float*)d_in[3];
    const float* rois = (const float*)d_in[4];
    float* out = (float*)d_out;
    const int n_rois = in_sizes[4] / 4;     // B*R = 2000
    roialign_kernel<<<n_rois, 256, 0, stream>>>(p2, p3, p4, p5, rois, out);
}

// Round 2
// 339.557 us; speedup vs baseline: 1.0354x; 1.0354x over previous
//
#include <hip/hip_runtime.h>

#define P 7
#define PP 49            // 7*7 pixels per ROI
#define CMAX 256         // channels
#define ACTIVE 245       // 5 channels * 49 pixels per iteration

// 8B vector with 4B alignment: lets the compiler emit one (unaligned-capable)
// global_load_dwordx2 for the (x0, x0+1) pair. x0==H-1 edge: lx==0 so the
// right-neighbor weight is 0 and the extra element (still inside the
// allocation) contributes nothing.
typedef float f2 __attribute__((ext_vector_type(2), aligned(4)));

struct PixParam { int o00, o10; float w00, w01, w10, w11; };

__global__ __launch_bounds__(256) void roialign_kernel(
    const float* __restrict__ p2, const float* __restrict__ p3,
    const float* __restrict__ p4, const float* __restrict__ p5,
    const float* __restrict__ rois, float* __restrict__ out)
{
    __shared__ PixParam sp[PP];

    const int r = blockIdx.x;     // roi index in [0, B*R)
    const int t = threadIdx.x;

    // --- per-ROI params (computed redundantly by all threads; broadcast loads) ---
    const float x1 = rois[r * 4 + 0];
    const float y1 = rois[r * 4 + 1];
    const float x2 = rois[r * 4 + 2];
    const float y2 = rois[r * 4 + 3];

    const float area = __fmul_rn(__fsub_rn(y2, y1), __fsub_rn(x2, x1));
    int lvl = (int)rintf(log2f(sqrtf(fmaxf(area, 0.0f)) / 224.0f)) + 4;
    lvl = lvl < 2 ? 2 : (lvl > 5 ? 5 : lvl);
    const int H = 1024 >> lvl;          // square feature maps: W == H
    const int HW = H * H;
    const float* fm = (lvl == 2) ? p2 : (lvl == 3) ? p3 : (lvl == 4) ? p4 : p5;
    // image 0 only (reference uses feature_maps[i][0] for all rois)

    // --- per-pixel params into LDS (49 threads) ---
    if (t < PP) {
        const int py = t / P, px = t % P;
        const float inv = 1.0f / 1024.0f;                 // exact pow2
        const float by1 = __fmul_rn(y1, inv), bx1 = __fmul_rn(x1, inv);
        const float by2 = __fmul_rn(y2, inv), bx2 = __fmul_rn(x2, inv);
        const float Hm1 = (float)(H - 1);
        const float ty = (float)py / 6.0f;
        const float tx = (float)px / 6.0f;
        // match numpy op-for-op (no fma contraction)
        const float vy = __fmul_rn(__fadd_rn(by1, __fmul_rn(ty, __fsub_rn(by2, by1))), Hm1);
        const float vx = __fmul_rn(__fadd_rn(bx1, __fmul_rn(tx, __fsub_rn(bx2, bx1))), Hm1);
        const bool vldy = (vy >= 0.0f) && (vy <= Hm1);
        const bool vldx = (vx >= 0.0f) && (vx <= Hm1);
        const float yc = fminf(fmaxf(vy, 0.0f), Hm1);
        const float xc = fminf(fmaxf(vx, 0.0f), Hm1);
        const int y0 = (int)floorf(yc);
        const int x0 = (int)floorf(xc);
        const int y1i = min(y0 + 1, H - 1);
        const float ly = __fsub_rn(yc, (float)y0);
        const float lx = __fsub_rn(xc, (float)x0);   // == 0 when x0 == H-1
        const float m = (vldy && vldx) ? 1.0f : 0.0f;
        const float wy0 = m * (1.0f - ly), wy1 = m * ly;
        const float wx0 = 1.0f - lx,      wx1 = lx;
        PixParam pp;
        pp.o00 = y0 * H + x0;           // pair (o00, o00+1) loaded as f2
        pp.o10 = y1i * H + x0;          // pair (o10, o10+1) loaded as f2
        pp.w00 = wy0 * wx0;     pp.w01 = wy0 * wx1;
        pp.w10 = wy1 * wx0;     pp.w11 = wy1 * wx1;
        sp[t] = pp;
    }
    __syncthreads();

    if (t >= ACTIVE) return;
    const int pix = t % PP;
    const int c0  = t / PP;                 // 0..4
    const PixParam pp = sp[pix];

    const float* fmc = fm + (size_t)c0 * HW;
    float* outr = out + (size_t)r * (CMAX * PP);
    int idx = t;                            // == c0*49 + pix
    #pragma unroll 8
    for (int c = c0; c < CMAX; c += 5) {
        const f2 tp = *(const f2*)(fmc + pp.o00);
        const f2 bt = *(const f2*)(fmc + pp.o10);
        outr[idx] = tp.x * pp.w00 + tp.y * pp.w01 + bt.x * pp.w10 + bt.y * pp.w11;
        fmc += 5 * HW;
        idx += ACTIVE;
    }
}

extern "C" void kernel_launch(void* const* d_in, const int* in_sizes, int n_in,
                              void* d_out, int out_size, void* d_ws, size_t ws_size,
                              hipStream_t stream) {
    const float* p2   = (const float*)d_in[0];
    const float* p3   = (const float*)d_in[1];
    const float* p4   = (const float*)d_in[2];
    const float* p5   = (const float*)d_in[3];
    const float* rois = (const float*)d_in[4];
    float* out = (float*)d_out;
    const int n_rois = in_sizes[4] / 4;     // B*R = 2000
    roialign_kernel<<<n_rois, 256, 0, stream>>>(p2, p3, p4, p5, rois, out);
}

// Round 3
// 335.570 us; speedup vs baseline: 1.0477x; 1.0119x over previous
//
#include <hip/hip_runtime.h>

#define P 7
#define PP 49            // 7*7 pixels per ROI
#define CMAX 256         // channels
#define ACTIVE 245       // 5 channels * 49 pixels per iteration
#define PIPE 8           // software-pipeline depth (pow2)
#define KTOT 52          // uniform trip count; store predicated on c<256

// 8B vector, 4B-aligned: (x0, x0+1) pair in one load. x0==H-1 edge: lx==0 so
// the extra element (still inside the allocation) has zero weight.
typedef float f2 __attribute__((ext_vector_type(2), aligned(4)));

struct PixParam { int o00, o10; float w00, w01, w10, w11; };

__global__ __launch_bounds__(256) void roialign_kernel(
    const float* __restrict__ p2, const float* __restrict__ p3,
    const float* __restrict__ p4, const float* __restrict__ p5,
    const float* __restrict__ rois, float* __restrict__ out)
{
    __shared__ PixParam sp[PP];

    const int r = blockIdx.x;     // roi index in [0, B*R)
    const int t = threadIdx.x;

    // --- per-ROI params (redundant per-thread; broadcast loads) ---
    const float x1 = rois[r * 4 + 0];
    const float y1 = rois[r * 4 + 1];
    const float x2 = rois[r * 4 + 2];
    const float y2 = rois[r * 4 + 3];

    const float area = __fmul_rn(__fsub_rn(y2, y1), __fsub_rn(x2, x1));
    int lvl = (int)rintf(log2f(sqrtf(fmaxf(area, 0.0f)) / 224.0f)) + 4;
    lvl = lvl < 2 ? 2 : (lvl > 5 ? 5 : lvl);
    const int H = 1024 >> lvl;          // square maps: W == H
    const int HW = H * H;
    const float* fm = (lvl == 2) ? p2 : (lvl == 3) ? p3 : (lvl == 4) ? p4 : p5;
    // image 0 only (reference uses feature_maps[i][0] for all rois)

    // --- per-pixel params into LDS (49 threads) ---
    if (t < PP) {
        const int py = t / P, px = t % P;
        const float inv = 1.0f / 1024.0f;                 // exact pow2
        const float by1 = __fmul_rn(y1, inv), bx1 = __fmul_rn(x1, inv);
        const float by2 = __fmul_rn(y2, inv), bx2 = __fmul_rn(x2, inv);
        const float Hm1 = (float)(H - 1);
        const float ty = (float)py / 6.0f;
        const float tx = (float)px / 6.0f;
        // match numpy op-for-op (no fma contraction)
        const float vy = __fmul_rn(__fadd_rn(by1, __fmul_rn(ty, __fsub_rn(by2, by1))), Hm1);
        const float vx = __fmul_rn(__fadd_rn(bx1, __fmul_rn(tx, __fsub_rn(bx2, bx1))), Hm1);
        const bool vldy = (vy >= 0.0f) && (vy <= Hm1);
        const bool vldx = (vx >= 0.0f) && (vx <= Hm1);
        const float yc = fminf(fmaxf(vy, 0.0f), Hm1);
        const float xc = fminf(fmaxf(vx, 0.0f), Hm1);
        const int y0 = (int)floorf(yc);
        const int x0 = (int)floorf(xc);
        const int y1i = min(y0 + 1, H - 1);
        const float ly = __fsub_rn(yc, (float)y0);
        const float lx = __fsub_rn(xc, (float)x0);   // == 0 when x0 == H-1
        const float m = (vldy && vldx) ? 1.0f : 0.0f;
        const float wy0 = m * (1.0f - ly), wy1 = m * ly;
        const float wx0 = 1.0f - lx,      wx1 = lx;
        PixParam pp;
        pp.o00 = y0 * H + x0;           // pair (o00, o00+1)
        pp.o10 = y1i * H + x0;          // pair (o10, o10+1)
        pp.w00 = wy0 * wx0;     pp.w01 = wy0 * wx1;
        pp.w10 = wy1 * wx0;     pp.w11 = wy1 * wx1;
        sp[t] = pp;
    }
    __syncthreads();

    if (t >= ACTIVE) return;
    const int pix = t % PP;
    const int c0  = t / PP;                 // 0..4
    const PixParam pp = sp[pix];

    // Two running gather pointers, advanced by 5 channel planes per iter.
    const float* pT = fm + (size_t)c0 * HW + pp.o00;
    const float* pB = fm + (size_t)c0 * HW + pp.o10;
    const size_t step = (size_t)5 * HW;

    // ---- manual 8-deep software pipeline: keep 16 loads in flight ----
    f2 tb[PIPE], bb[PIPE];
    #pragma unroll
    for (int k = 0; k < PIPE; ++k) {
        tb[k] = *(const f2*)pT;
        bb[k] = *(const f2*)pB;
        pT += step; pB += step;
    }
    // Loads for k >= 52-PIPE reach channels up to c0+255 (<260): beyond image-0
    // channels but inside the B=2 allocation; their stores are predicated off.

    float* outr = out + (size_t)r * (CMAX * PP);
    int idx = t;                            // == c0*49 + pix
    #pragma unroll
    for (int k = 0; k < KTOT; ++k) {
        const f2 tp = tb[k & (PIPE - 1)];
        const f2 bt = bb[k & (PIPE - 1)];
        if (k + PIPE < KTOT) {              // refill the ring slot
            tb[k & (PIPE - 1)] = *(const f2*)pT;
            bb[k & (PIPE - 1)] = *(const f2*)pB;
            pT += step; pB += step;
        }
        const float v = tp.x * pp.w00 + tp.y * pp.w01
                      + bt.x * pp.w10 + bt.y * pp.w11;
        if (c0 + 5 * k < CMAX) {            // false only for k==51, c0>0
            outr[idx] = v;
        }
        idx += ACTIVE;
    }
}

extern "C" void kernel_launch(void* const* d_in, const int* in_sizes, int n_in,
                              void* d_out, int out_size, void* d_ws, size_t ws_size,
                              hipStream_t stream) {
    const float* p2   = (const float*)d_in[0];
    const float* p3   = (const float*)d_in[1];
    const float* p4   = (const float*)d_in[2];
    const float* p5   = (const float*)d_in[3];
    const float* rois = (const float*)d_in[4];
    float* out = (float*)d_out;
    const int n_rois = in_sizes[4] / 4;     // B*R = 2000
    roialign_kernel<<<n_rois, 256, 0, stream>>>(p2, p3, p4, p5, rois, out);
}

// Round 4
// 300.290 us; speedup vs baseline: 1.1708x; 1.1175x over previous
//
#include <hip/hip_runtime.h>

#define P 7
#define PP 49            // 7*7 pixels per ROI
#define CMAX 256         // channels
#define G 8              // ROIs per cluster (per block)
#define CSPLIT 8         // channel slices -> CMAX/CSPLIT channels per block
#define CSLICE 32        // channels per block
#define NBINS 256        // 4 levels x 8x8 spatial cells

// d_ws layout in u32 words:
//   [0,256)      hist
//   [256,512)    cursor (exclusive prefix of hist; scatter bumps it)
//   [512,2560)   bucket id per roi (capacity 2048)
//   [2560,4608)  perm (sorted roi indices)
#define WS_HIST   0
#define WS_CURSOR 256
#define WS_BUCKET 512
#define WS_PERM   2560

// 8B vector, 4B-aligned: (x0, x0+1) pair in one load. x0==H-1 edge: lx==0 so
// the extra element (still inside the allocation) has zero weight.
typedef float f2 __attribute__((ext_vector_type(2), aligned(4)));

struct PixParam { int o00, o10; float w00, w01, w10, w11; };

__device__ __forceinline__ int roi_level(float x1, float y1, float x2, float y2) {
    const float area = __fmul_rn(__fsub_rn(y2, y1), __fsub_rn(x2, x1));
    int lvl = (int)rintf(log2f(sqrtf(fmaxf(area, 0.0f)) / 224.0f)) + 4;
    return lvl < 2 ? 2 : (lvl > 5 ? 5 : lvl);
}

__global__ void zero_kernel(unsigned* ws) {
    ws[WS_HIST + threadIdx.x] = 0u;     // 256 threads
}

__global__ void hist_kernel(const float* __restrict__ rois, int n, unsigned* ws) {
    const int r = blockIdx.x * blockDim.x + threadIdx.x;
    if (r >= n) return;
    const float x1 = rois[r*4+0], y1 = rois[r*4+1], x2 = rois[r*4+2], y2 = rois[r*4+3];
    const int lvl = roi_level(x1, y1, x2, y2);
    int cx = ((int)(__fmul_rn(__fadd_rn(x1, x2), 0.5f))) >> 7; cx = min(cx, 7);
    int cy = ((int)(__fmul_rn(__fadd_rn(y1, y2), 0.5f))) >> 7; cy = min(cy, 7);
    const int b = ((lvl - 2) << 6) | (cy << 3) | cx;
    ws[WS_BUCKET + r] = (unsigned)b;
    atomicAdd(&ws[WS_HIST + b], 1u);
}

__global__ void scan_kernel(unsigned* ws) {
    __shared__ unsigned s[NBINS];
    const int t = threadIdx.x;          // 256 threads
    const unsigned h = ws[WS_HIST + t];
    s[t] = h;
    __syncthreads();
    for (int off = 1; off < NBINS; off <<= 1) {
        const unsigned v = (t >= off) ? s[t - off] : 0u;
        __syncthreads();
        s[t] += v;
        __syncthreads();
    }
    ws[WS_CURSOR + t] = s[t] - h;       // exclusive prefix
}

__global__ void scatter_kernel(int n, unsigned* ws) {
    const int r = blockIdx.x * blockDim.x + threadIdx.x;
    if (r >= n) return;
    const unsigned b = ws[WS_BUCKET + r];
    const unsigned pos = atomicAdd(&ws[WS_CURSOR + b], 1u);
    ws[WS_PERM + pos] = (unsigned)r;
}

__global__ __launch_bounds__(256) void roialign_main(
    const float* __restrict__ p2, const float* __restrict__ p3,
    const float* __restrict__ p4, const float* __restrict__ p5,
    const float* __restrict__ rois, const unsigned* __restrict__ ws,
    float* __restrict__ out, int n)
{
    __shared__ PixParam sp[G * PP];
    __shared__ const float* fm_s[G];
    __shared__ int hw_s[G];
    __shared__ long long obase_s[G];

    const int nclust = (n + G - 1) / G;          // 250 for n=2000
    const int cl = blockIdx.x % nclust;          // cluster id
    const int cb = blockIdx.x / nclust;          // channel slice 0..CSPLIT-1
    const int t  = threadIdx.x;

    // ---- per-(roi,pixel) params into LDS ----
    for (int idx = t; idx < G * PP; idx += 256) {
        const int g = idx / PP, pix = idx % PP;
        const int gi = cl * G + g;
        PixParam pp; pp.o00 = 0; pp.o10 = 0;
        pp.w00 = 0.f; pp.w01 = 0.f; pp.w10 = 0.f; pp.w11 = 0.f;
        if (gi < n) {
            const int rr = (int)ws[WS_PERM + gi];
            const float x1 = rois[rr*4+0], y1 = rois[rr*4+1];
            const float x2 = rois[rr*4+2], y2 = rois[rr*4+3];
            const int lvl = roi_level(x1, y1, x2, y2);
            const int H = 1024 >> lvl;
            const float* fm = (lvl == 2) ? p2 : (lvl == 3) ? p3 : (lvl == 4) ? p4 : p5;

            const int py = pix / P, px = pix % P;
            const float inv = 1.0f / 1024.0f;               // exact pow2
            const float by1 = __fmul_rn(y1, inv), bx1 = __fmul_rn(x1, inv);
            const float by2 = __fmul_rn(y2, inv), bx2 = __fmul_rn(x2, inv);
            const float Hm1 = (float)(H - 1);
            const float ty = (float)py / 6.0f;
            const float tx = (float)px / 6.0f;
            // match numpy op-for-op (no fma contraction)
            const float vy = __fmul_rn(__fadd_rn(by1, __fmul_rn(ty, __fsub_rn(by2, by1))), Hm1);
            const float vx = __fmul_rn(__fadd_rn(bx1, __fmul_rn(tx, __fsub_rn(bx2, bx1))), Hm1);
            const bool vldy = (vy >= 0.0f) && (vy <= Hm1);
            const bool vldx = (vx >= 0.0f) && (vx <= Hm1);
            const float yc = fminf(fmaxf(vy, 0.0f), Hm1);
            const float xc = fminf(fmaxf(vx, 0.0f), Hm1);
            const int y0 = (int)floorf(yc);
            const int x0 = (int)floorf(xc);
            const int y1i = min(y0 + 1, H - 1);
            const float ly = __fsub_rn(yc, (float)y0);
            const float lx = __fsub_rn(xc, (float)x0);      // == 0 when x0 == H-1
            const float m = (vldy && vldx) ? 1.0f : 0.0f;
            const float wy0 = m * (1.0f - ly), wy1 = m * ly;
            const float wx0 = 1.0f - lx,      wx1 = lx;
            pp.o00 = y0 * H + x0;
            pp.o10 = y1i * H + x0;
            pp.w00 = wy0 * wx0;  pp.w01 = wy0 * wx1;
            pp.w10 = wy1 * wx0;  pp.w11 = wy1 * wx1;
            if (pix == 0) {
                fm_s[g] = fm;
                hw_s[g] = H * H;
                obase_s[g] = (long long)rr * (CMAX * PP);
            }
        } else if (pix == 0) {
            fm_s[g] = p2; hw_s[g] = 0; obase_s[g] = -1;
        }
        sp[idx] = pp;
    }
    __syncthreads();

    if (t >= 5 * PP) return;            // 245 active
    const int pix = t % PP;
    const int c0  = t / PP;             // 0..4

    // ---- hoist per-g state into registers ----
    const float* pT[G]; const float* pB[G];
    size_t step[G];
    float w00[G], w01[G], w10[G], w11[G];
    long long ob[G];
    #pragma unroll
    for (int g = 0; g < G; ++g) {
        const PixParam pp = sp[g * PP + pix];
        const int hw = hw_s[g];
        const float* base = fm_s[g] + (size_t)(cb * CSLICE + c0) * hw;
        pT[g] = base + pp.o00;
        pB[g] = base + pp.o10;
        step[g] = (size_t)5 * hw;
        w00[g] = pp.w00; w01[g] = pp.w01; w10[g] = pp.w10; w11[g] = pp.w11;
        ob[g] = obase_s[g];
    }

    // ---- channel loop (32 channels: c_local = c0 + 5k < 32) ----
    #pragma unroll
    for (int k = 0; k < 7; ++k) {
        const int clc = c0 + 5 * k;
        if (clc < CSLICE) {             // false only at k==6 for c0>=2 (exec-masked)
            f2 tp[G], bt[G];
            #pragma unroll
            for (int g = 0; g < G; ++g) {       // issue all 16 loads first
                tp[g] = *(const f2*)pT[g];
                bt[g] = *(const f2*)pB[g];
                pT[g] += step[g]; pB[g] += step[g];
            }
            #pragma unroll
            for (int g = 0; g < G; ++g) {       // then consume
                const float v = tp[g].x * w00[g] + tp[g].y * w01[g]
                              + bt[g].x * w10[g] + bt[g].y * w11[g];
                if (ob[g] >= 0) {
                    out[ob[g] + (long long)(cb * CSLICE + clc) * PP + pix] = v;
                }
            }
        }
    }
}

extern "C" void kernel_launch(void* const* d_in, const int* in_sizes, int n_in,
                              void* d_out, int out_size, void* d_ws, size_t ws_size,
                              hipStream_t stream) {
    const float* p2   = (const float*)d_in[0];
    const float* p3   = (const float*)d_in[1];
    const float* p4   = (const float*)d_in[2];
    const float* p5   = (const float*)d_in[3];
    const float* rois = (const float*)d_in[4];
    float* out = (float*)d_out;
    unsigned* ws = (unsigned*)d_ws;
    const int n = in_sizes[4] / 4;            // B*R = 2000

    const int nb = (n + 255) / 256;
    zero_kernel<<<1, NBINS, 0, stream>>>(ws);
    hist_kernel<<<nb, 256, 0, stream>>>(rois, n, ws);
    scan_kernel<<<1, NBINS, 0, stream>>>(ws);
    scatter_kernel<<<nb, 256, 0, stream>>>(n, ws);

    const int nclust = (n + G - 1) / G;       // 250
    roialign_main<<<nclust * CSPLIT, 256, 0, stream>>>(p2, p3, p4, p5, rois, ws, out, n);
}